// Round 2
// baseline (228.118 us; speedup 1.0000x reference)
//
#include <hip/hip_runtime.h>
#include <math.h>

#define N_IN  96
#define N_OUT 192

__device__ __forceinline__ int fold_dct2(int idx, int n) {
    int p = 2 * n;
    int m = ((idx % p) + p) % p;
    return (m >= n) ? (p - 1 - m) : m;
}

// Build resize matrix B [192][96] in double (dct2-folded cubic B-spline taps).
__global__ void build_B_kernel(double* __restrict__ Bd) {
    int j = blockIdx.x * blockDim.x + threadIdx.x;
    if (j >= N_OUT) return;
    double x  = (double)j * (double)(N_IN - 1) / (double)(N_OUT - 1);
    double bf = floor(x);
    int    b  = (int)bf;
    double t  = x - bf;
    double t2 = t * t, t3 = t2 * t;
    double w0 = (1.0 - t) * (1.0 - t) * (1.0 - t) / 6.0;
    double w1 = (3.0 * t3 - 6.0 * t2 + 4.0) / 6.0;
    double w2 = (-3.0 * t3 + 3.0 * t2 + 3.0 * t + 1.0) / 6.0;
    double w3 = t3 / 6.0;
    double w[4] = {w0, w1, w2, w3};
    for (int k = 0; k < 4; ++k) {
        int c = fold_dct2(b - 1 + k, N_IN);
        Bd[j * N_IN + c] += w[k];  // row owned by this thread; Bd pre-zeroed
    }
}

// Solve A * M^T = B^T (A = spline interpolation operator, tridiagonal with
// dct2 boundary: diag 2/3 except 5/6 at both ends, off-diag 1/6).
// Thread j runs a Thomas solve on RHS = B[j,:], yielding M[j,:].
// Output MT[x*192 + j] = M[j][x] (float), coalesced for the GEMM passes.
__global__ void solve_M_kernel(const double* __restrict__ Bd,
                               double* __restrict__ DP,
                               float* __restrict__ MT) {
    __shared__ double cp[N_IN];
    __shared__ double minv[N_IN];
    int j = threadIdx.x;  // 192 threads, 1 block
    if (j == 0) {
        const double a = 1.0 / 6.0;
        double b0 = 5.0 / 6.0;
        minv[0] = 1.0 / b0;
        cp[0]   = a * minv[0];
        for (int i = 1; i < N_IN; ++i) {
            double bi  = (i == N_IN - 1) ? (5.0 / 6.0) : (2.0 / 3.0);
            double den = bi - a * cp[i - 1];
            minv[i] = 1.0 / den;
            cp[i]   = a * minv[i];
        }
    }
    __syncthreads();
    const double a = 1.0 / 6.0;
    double dp = Bd[j * N_IN + 0] * minv[0];
    DP[0 * N_OUT + j] = dp;
    for (int i = 1; i < N_IN; ++i) {
        dp = (Bd[j * N_IN + i] - a * dp) * minv[i];
        DP[i * N_OUT + j] = dp;
    }
    double xv = DP[(N_IN - 1) * N_OUT + j];
    MT[(N_IN - 1) * N_OUT + j] = (float)xv;
    for (int i = N_IN - 2; i >= 0; --i) {
        xv = DP[i * N_OUT + j] - cp[i] * xv;
        MT[i * N_OUT + j] = (float)xv;
    }
}

// Contract a non-innermost axis: in [outer][96][INNER] -> out [outer][192][INNER].
// Lanes across flattened (outer, inner) columns -> coalesced global loads;
// 8 output rows per thread; M loads are block-uniform -> scalar loads.
template <int INNER>
__global__ __launch_bounds__(256)
void contract_mid_kernel(const float* __restrict__ in, float* __restrict__ out,
                         const float* __restrict__ MT, int total) {
    int q = blockIdx.x * 256 + threadIdx.x;
    if (q >= total) return;
    int o = q / INNER;
    int r = q - o * INNER;
    int i0 = blockIdx.y * 8;
    const float* ip = in + (size_t)o * N_IN * INNER + r;
    float acc[8] = {0.f, 0.f, 0.f, 0.f, 0.f, 0.f, 0.f, 0.f};
    for (int x = 0; x < N_IN; ++x) {
        float v = ip[(size_t)x * INNER];
        const float* mrow = MT + x * N_OUT + i0;  // block-uniform address
#pragma unroll
        for (int ii = 0; ii < 8; ++ii) acc[ii] += mrow[ii] * v;
    }
    float* op = out + (size_t)o * N_OUT * INNER + (size_t)i0 * INNER + r;
#pragma unroll
    for (int ii = 0; ii < 8; ++ii) op[(size_t)ii * INNER] = acc[ii];
}

// Contract the innermost axis: in [rows][96] -> out [rows][192].
// Lanes across the 192 output columns (MT coalesced); 8 rows per block via
// block-uniform scalar loads of the input row values.
__global__ __launch_bounds__(192)
void contract_last_kernel(const float* __restrict__ in, float* __restrict__ out,
                          const float* __restrict__ MT) {
    int k = threadIdx.x;  // 0..191
    size_t row0 = (size_t)blockIdx.x * 8;
    const float* ip = in + row0 * N_IN;
    float acc[8] = {0.f, 0.f, 0.f, 0.f, 0.f, 0.f, 0.f, 0.f};
    for (int z = 0; z < N_IN; ++z) {
        float m = MT[z * N_OUT + k];  // coalesced
#pragma unroll
        for (int r = 0; r < 8; ++r) acc[r] += ip[(size_t)r * N_IN + z] * m;
    }
    float* op = out + row0 * N_OUT + k;
#pragma unroll
    for (int r = 0; r < 8; ++r) op[(size_t)r * N_OUT] = acc[r];
}

extern "C" void kernel_launch(void* const* d_in, const int* in_sizes, int n_in,
                              void* d_out, int out_size, void* d_ws, size_t ws_size,
                              hipStream_t stream) {
    const float* in  = (const float*)d_in[0];
    float*       out = (float*)d_out;
    char*        ws  = (char*)d_ws;

    // ws layout (bytes):
    //   T1: [4][192][96][96] f32  = 28,311,552
    //   T2: [4][192][192][96] f32 = 56,623,104 (offset 28,311,552)
    //   MT: [96][192] f32         =     73,728 (offset 84,934,656)
    //   Bd: [192][96] f64         =    147,456 (offset 85,008,384)
    //   DP: [96][192] f64         =    147,456 (offset 85,155,840)
    float*  T1 = (float*)(ws + 0);
    float*  T2 = (float*)(ws + 28311552);
    float*  MT = (float*)(ws + 84934656);
    double* Bd = (double*)(ws + 85008384);
    double* DP = (double*)(ws + 85155840);

    // Build the combined per-axis operator M = B_resize * A^-1 (192x96).
    (void)hipMemsetAsync(Bd, 0, (size_t)N_OUT * N_IN * sizeof(double), stream);
    build_B_kernel<<<1, N_OUT, 0, stream>>>(Bd);
    solve_M_kernel<<<1, N_OUT, 0, stream>>>(Bd, DP, MT);

    // Pass 1: contract axis-x. in [4][96][9216] -> T1 [4][192][9216]
    {
        int total = 4 * 9216;
        dim3 g(total / 256, N_OUT / 8, 1);
        contract_mid_kernel<9216><<<g, 256, 0, stream>>>(in, T1, MT, total);
    }
    // Pass 2: contract axis-y. T1 [768][96][96] -> T2 [768][192][96]
    {
        int total = 768 * 96;
        dim3 g(total / 256, N_OUT / 8, 1);
        contract_mid_kernel<96><<<g, 256, 0, stream>>>(T1, T2, MT, total);
    }
    // Pass 3: contract axis-z. T2 [147456][96] -> out [147456][192]
    {
        contract_last_kernel<<<147456 / 8, N_OUT, 0, stream>>>(T2, out, MT);
    }
}

// Round 3
// 102.505 us; speedup vs baseline: 2.2254x; 2.2254x over previous
//
#include <hip/hip_runtime.h>
#include <math.h>

#define N_IN  96
#define N_OUT 192
#define BW    24   // truncated band window width

__device__ __forceinline__ int fold_dct2(int idx, int n) {
    int p = 2 * n;
    int m = ((idx % p) + p) % p;
    return (m >= n) ? (p - 1 - m) : m;
}

// Build resize matrix B [192][96] in double (dct2-folded cubic B-spline taps).
__global__ void build_B_kernel(double* __restrict__ Bd) {
    int j = blockIdx.x * blockDim.x + threadIdx.x;
    if (j >= N_OUT) return;
    double x  = (double)j * (double)(N_IN - 1) / (double)(N_OUT - 1);
    double bf = floor(x);
    int    b  = (int)bf;
    double t  = x - bf;
    double t2 = t * t, t3 = t2 * t;
    double w0 = (1.0 - t) * (1.0 - t) * (1.0 - t) / 6.0;
    double w1 = (3.0 * t3 - 6.0 * t2 + 4.0) / 6.0;
    double w2 = (-3.0 * t3 + 3.0 * t2 + 3.0 * t + 1.0) / 6.0;
    double w3 = t3 / 6.0;
    double w[4] = {w0, w1, w2, w3};
    for (int k = 0; k < 4; ++k) {
        int c = fold_dct2(b - 1 + k, N_IN);
        Bd[j * N_IN + c] += w[k];  // row owned by this thread; Bd pre-zeroed
    }
}

// Solve A * M^T = B^T (A tridiag: diag 2/3 except 5/6 at ends, off-diag 1/6).
// Thread j: Thomas solve on RHS = B[j,:], output MT[x*192+j] = M[j][x] (f32).
__global__ void solve_M_kernel(const double* __restrict__ Bd,
                               double* __restrict__ DP,
                               float* __restrict__ MT) {
    __shared__ double cp[N_IN];
    __shared__ double minv[N_IN];
    int j = threadIdx.x;  // 192 threads, 1 block
    if (j == 0) {
        const double a = 1.0 / 6.0;
        double b0 = 5.0 / 6.0;
        minv[0] = 1.0 / b0;
        cp[0]   = a * minv[0];
        for (int i = 1; i < N_IN; ++i) {
            double bi  = (i == N_IN - 1) ? (5.0 / 6.0) : (2.0 / 3.0);
            double den = bi - a * cp[i - 1];
            minv[i] = 1.0 / den;
            cp[i]   = a * minv[i];
        }
    }
    __syncthreads();
    const double a = 1.0 / 6.0;
    double dp = Bd[j * N_IN + 0] * minv[0];
    DP[0 * N_OUT + j] = dp;
    for (int i = 1; i < N_IN; ++i) {
        dp = (Bd[j * N_IN + i] - a * dp) * minv[i];
        DP[i * N_OUT + j] = dp;
    }
    double xv = DP[(N_IN - 1) * N_OUT + j];
    MT[(N_IN - 1) * N_OUT + j] = (float)xv;
    for (int i = N_IN - 2; i >= 0; --i) {
        xv = DP[i * N_OUT + j] - cp[i] * xv;
        MT[i * N_OUT + j] = (float)xv;
    }
}

// Extract banded weights from dense M. Windows:
//  - oct-aligned (8 output rows share a window start)  -> WB8 [192][24], S8[24]
//  - quad-aligned, start forced to multiple of 4 (16B) -> WT4 [24][192], S4[48]
__global__ void extract_band_kernel(const float* __restrict__ MT,
                                    float* __restrict__ WB8,
                                    float* __restrict__ WT4,
                                    int* __restrict__ S8,
                                    int* __restrict__ S4) {
    int j = threadIdx.x;
    if (j >= N_OUT) return;
    int j8 = j & ~7;
    int b8 = (int)floor((double)j8 * 95.0 / 191.0);
    int s8 = b8 - 9; s8 = s8 < 0 ? 0 : (s8 > 72 ? 72 : s8);
    int j4 = j & ~3;
    int b4 = (int)floor((double)j4 * 95.0 / 191.0);
    int s4 = b4 - 9; s4 = s4 < 0 ? 0 : (s4 > 72 ? 72 : s4);
    s4 &= ~3;
    for (int t = 0; t < BW; ++t) {
        WB8[j * BW + t]    = MT[(s8 + t) * N_OUT + j];
        WT4[t * N_OUT + j] = MT[(s4 + t) * N_OUT + j];
    }
    if ((j & 7) == 0) S8[j >> 3] = s8;
    if ((j & 3) == 0) S4[j >> 2] = s4;
}

// Banded mid-axis contraction: in [OUTER][96][QUADS*4] -> out [OUTER][192][QUADS*4].
// Thread: one (outer, float4 column) x 8 output rows (one oct). 24 float4 loads,
// 768 FMA, block-uniform weight loads.
template <int QUADS>
__global__ __launch_bounds__(256)
void pass_mid_kernel(const float4* __restrict__ in, float4* __restrict__ out,
                     const float* __restrict__ WB8, const int* __restrict__ S8) {
    int g  = blockIdx.x * 256 + threadIdx.x;
    int o  = g / QUADS;
    int q  = g - o * QUADS;
    int og = blockIdx.y;      // oct index 0..23
    int j0 = og * 8;
    int S  = S8[og];
    const float4* ip = in + ((size_t)o * N_IN + S) * QUADS + q;
    float4 acc[8];
#pragma unroll
    for (int jj = 0; jj < 8; ++jj) acc[jj] = make_float4(0.f, 0.f, 0.f, 0.f);
#pragma unroll
    for (int t = 0; t < BW; ++t) {
        float4 v = ip[(size_t)t * QUADS];
#pragma unroll
        for (int jj = 0; jj < 8; ++jj) {
            float w = WB8[(j0 + jj) * BW + t];
            acc[jj].x += w * v.x; acc[jj].y += w * v.y;
            acc[jj].z += w * v.z; acc[jj].w += w * v.w;
        }
    }
    float4* op = out + ((size_t)o * N_OUT + j0) * QUADS + q;
#pragma unroll
    for (int jj = 0; jj < 8; ++jj) op[(size_t)jj * QUADS] = acc[jj];
}

// Banded innermost-axis contraction: in [rows][96] -> out [rows][192].
// Thread: 4 consecutive z' (one quad, shared 4-aligned window) x 8 rows.
// Weights: 24 coalesced float4 loads held in registers. Rows: 6 float4 loads
// each. All stores coalesced float4.
__global__ __launch_bounds__(256)
void pass_last_kernel(const float* __restrict__ in, float* __restrict__ out,
                      const float* __restrict__ WT4, const int* __restrict__ S4) {
    int g  = blockIdx.x * 256 + threadIdx.x;
    int jq = g % 48;
    int r8 = g / 48;
    int j0 = jq * 4;
    int S  = S4[jq];
    float4 w[BW];
#pragma unroll
    for (int t = 0; t < BW; ++t)
        w[t] = *(const float4*)(WT4 + t * N_OUT + j0);
    const float* ipb = in + (size_t)r8 * 8 * N_IN + S;
    float4 acc[8];
#pragma unroll
    for (int r = 0; r < 8; ++r) acc[r] = make_float4(0.f, 0.f, 0.f, 0.f);
#pragma unroll
    for (int r = 0; r < 8; ++r) {
        const float4* ip = (const float4*)(ipb + (size_t)r * N_IN);
        float4 v0 = ip[0], v1 = ip[1], v2 = ip[2];
        float4 v3 = ip[3], v4 = ip[4], v5 = ip[5];
        float rv[BW] = {v0.x, v0.y, v0.z, v0.w, v1.x, v1.y, v1.z, v1.w,
                        v2.x, v2.y, v2.z, v2.w, v3.x, v3.y, v3.z, v3.w,
                        v4.x, v4.y, v4.z, v4.w, v5.x, v5.y, v5.z, v5.w};
#pragma unroll
        for (int t = 0; t < BW; ++t) {
            acc[r].x += w[t].x * rv[t];
            acc[r].y += w[t].y * rv[t];
            acc[r].z += w[t].z * rv[t];
            acc[r].w += w[t].w * rv[t];
        }
    }
#pragma unroll
    for (int r = 0; r < 8; ++r)
        *(float4*)(out + ((size_t)r8 * 8 + r) * N_OUT + j0) = acc[r];
}

extern "C" void kernel_launch(void* const* d_in, const int* in_sizes, int n_in,
                              void* d_out, int out_size, void* d_ws, size_t ws_size,
                              hipStream_t stream) {
    const float* in  = (const float*)d_in[0];
    float*       out = (float*)d_out;
    char*        ws  = (char*)d_ws;

    // ws layout (bytes):
    //   T1:  [4][192][96][96] f32   = 28,311,552 @ 0
    //   T2:  [4][192][192][96] f32  = 56,623,104 @ 28,311,552
    //   MT:  [96][192] f32          =     73,728 @ 84,934,656
    //   Bd:  [192][96] f64          =    147,456 @ 85,008,384  (dead after solve)
    //   DP:  [96][192] f64          =    147,456 @ 85,155,840  (dead after solve)
    //   band arrays overlap Bd region (extract runs after solve):
    //   WB8: [192][24] f32 = 18,432 @ 85,008,384
    //   WT4: [24][192] f32 = 18,432 @ 85,026,816
    //   S8:  [24] i32      @ 85,045,248
    //   S4:  [48] i32      @ 85,045,344
    float*  T1  = (float*)(ws + 0);
    float*  T2  = (float*)(ws + 28311552);
    float*  MT  = (float*)(ws + 84934656);
    double* Bd  = (double*)(ws + 85008384);
    double* DP  = (double*)(ws + 85155840);

    (void)hipMemsetAsync(Bd, 0, (size_t)N_OUT * N_IN * sizeof(double), stream);
    build_B_kernel<<<1, N_OUT, 0, stream>>>(Bd);
    solve_M_kernel<<<1, N_OUT, 0, stream>>>(Bd, DP, MT);

    float* WB8 = (float*)(ws + 85008384);
    float* WT4 = (float*)(ws + 85026816);
    int*   S8  = (int*)(ws + 85045248);
    int*   S4  = (int*)(ws + 85045344);
    extract_band_kernel<<<1, N_OUT, 0, stream>>>(MT, WB8, WT4, S8, S4);

    // Pass 1: x-axis. in [4][96][2304 quads] -> T1 [4][192][2304 quads]
    {
        dim3 g(4 * 2304 / 256, BW, 1);  // (36, 24)
        pass_mid_kernel<2304><<<g, 256, 0, stream>>>(
            (const float4*)in, (float4*)T1, WB8, S8);
    }
    // Pass 2: y-axis. T1 [768][96][24 quads] -> T2 [768][192][24 quads]
    {
        dim3 g(768 * 24 / 256, BW, 1);  // (72, 24)
        pass_mid_kernel<24><<<g, 256, 0, stream>>>(
            (const float4*)T1, (float4*)T2, WB8, S8);
    }
    // Pass 3: z-axis. T2 [147456][96] -> out [147456][192]
    {
        pass_last_kernel<<<(147456 / 8) * 48 / 256, 256, 0, stream>>>(
            T2, out, WT4, S4);
    }
}